// Round 1
// baseline (293.472 us; speedup 1.0000x reference)
//
#include <hip/hip_runtime.h>
#include <math.h>

// CapsNet dynamic routing, fused (no x_hat materialization).
//   x: [512,1152,8] f32, w: [10,1152,16,8] f32, out: [512,10,16] f32
// pass A: s0[b,c,d] = sum_n x_hat / 10  (c uniform since b=0)  -> squash -> o0
// pass B: b1[b,c,n] = o0 . x_hat ; c1 = softmax_c(b1) ; s1 = sum_n c1*x_hat -> squash -> out

#define BB   512
#define NN1  1152
#define DD1  8
#define CC2  10
#define DD2  16
#define CD   160            // CC2*DD2
#define BT   32             // batch tile per block
#define NBC  16             // BB/BT
#define NT   36             // n's per block
#define NNC  32             // NN1/NT
#define NSTG 4              // n's staged in LDS at a time
#define CSTR 132            // padded per-c LDS stride (16*8=128 -> 132, breaks bank aliasing)
#define SWN  (CC2*CSTR)     // 1320 floats per staged n
#define WCN  (NN1*DD2*DD1)  // 147456 floats per c in global w
#define XB   (NN1*DD1)      // 9216 floats per b in global x

// ---------------- pass A: s0 partial sums (raw, scale 0.1 applied in squash) ----------------
__global__ __launch_bounds__(256) void caps_pass_a(
    const float* __restrict__ x, const float* __restrict__ w, float* __restrict__ s0)
{
    __shared__ float sw[NSTG * SWN];        // [n_loc][c (stride 132)][d*8+k]
    __shared__ float sx[NSTG * BT * DD1];   // [n_loc][b_loc][k]

    const int bc = blockIdx.x >> 5;         // 16 b-chunks
    const int nc = blockIdx.x & 31;         // 32 n-chunks
    const int b0 = bc * BT, n0 = nc * NT;
    const int tid = threadIdx.x;
    const int tb = tid & 7;                 // 8 b-groups (b_loc = tb + 8*i, stride-8: bank-friendly)
    const int tc = tid >> 3;                // 32 cd-groups of 5

    float acc[4][5];
#pragma unroll
    for (int i = 0; i < 4; ++i)
#pragma unroll
        for (int j = 0; j < 5; ++j) acc[i][j] = 0.f;

    for (int st = 0; st < NT / NSTG; ++st) {
        const int nb = n0 + st * NSTG;
        // stage w: 10 c's x 4 n x 128 floats = 1280 float4
#pragma unroll
        for (int it = 0; it < 5; ++it) {
            int f = tid + it * 256;
            int c = f >> 7;                 // 128 float4 per c-chunk
            int j = (f & 127) << 2;         // float index within c-chunk [0,512)
            float4 v = *(const float4*)(w + c * WCN + nb * 128 + j);
            *(float4*)(sw + (j >> 7) * SWN + c * CSTR + (j & 127)) = v;
        }
        // stage x: 32 b x 4 n x 8 = 256 float4 (one per thread)
        {
            int bl = tid >> 3;
            int j = (tid & 7) << 2;         // [0,32) within b's 4n*8k chunk
            float4 v = *(const float4*)(x + (b0 + bl) * XB + nb * DD1 + j);
            *(float4*)(sx + (j >> 3) * (BT * DD1) + bl * DD1 + (j & 7)) = v;
        }
        __syncthreads();

#pragma unroll
        for (int nl = 0; nl < NSTG; ++nl) {
            float xr[4][8];
#pragma unroll
            for (int i = 0; i < 4; ++i) {
                const float* p = sx + nl * (BT * DD1) + (tb + 8 * i) * DD1;
                float4 a = *(const float4*)p, b = *(const float4*)(p + 4);
                xr[i][0] = a.x; xr[i][1] = a.y; xr[i][2] = a.z; xr[i][3] = a.w;
                xr[i][4] = b.x; xr[i][5] = b.y; xr[i][6] = b.z; xr[i][7] = b.w;
            }
#pragma unroll
            for (int j = 0; j < 5; ++j) {
                int cd = tc * 5 + j;
                const float* p = sw + nl * SWN + (cd >> 4) * CSTR + (cd & 15) * DD1;
                float4 a = *(const float4*)p, b = *(const float4*)(p + 4);
                float wr[8] = {a.x, a.y, a.z, a.w, b.x, b.y, b.z, b.w};
#pragma unroll
                for (int i = 0; i < 4; ++i) {
                    float s = acc[i][j];
#pragma unroll
                    for (int k = 0; k < 8; ++k) s += xr[i][k] * wr[k];
                    acc[i][j] = s;
                }
            }
        }
        __syncthreads();   // WAR: next stage overwrites sw/sx
    }

#pragma unroll
    for (int i = 0; i < 4; ++i)
#pragma unroll
        for (int j = 0; j < 5; ++j)
            atomicAdd(&s0[(b0 + tb + 8 * i) * CD + tc * 5 + j], acc[i][j]);
}

// ---------------- squash(0.1 * s0) in place ----------------
__global__ void caps_squash_a(float* __restrict__ s)
{
    int t = blockIdx.x * blockDim.x + threadIdx.x;
    if (t >= BB * CC2) return;
    float* p = s + t * DD2;
    float4 v0 = *(float4*)(p), v1 = *(float4*)(p + 4), v2 = *(float4*)(p + 8), v3 = *(float4*)(p + 12);
    float ss = v0.x*v0.x + v0.y*v0.y + v0.z*v0.z + v0.w*v0.w
             + v1.x*v1.x + v1.y*v1.y + v1.z*v1.z + v1.w*v1.w
             + v2.x*v2.x + v2.y*v2.y + v2.z*v2.z + v2.w*v2.w
             + v3.x*v3.x + v3.y*v3.y + v3.z*v3.z + v3.w*v3.w;
    float sq = 0.01f * ss;                       // |0.1*raw|^2
    float sc = sq / (1.f + sq) / sqrtf(ss);      // o = sc*raw  (0.1/sqrt(sq)=1/sqrt(ss))
    v0.x*=sc; v0.y*=sc; v0.z*=sc; v0.w*=sc; v1.x*=sc; v1.y*=sc; v1.z*=sc; v1.w*=sc;
    v2.x*=sc; v2.y*=sc; v2.z*=sc; v2.w*=sc; v3.x*=sc; v3.y*=sc; v3.z*=sc; v3.w*=sc;
    *(float4*)(p) = v0; *(float4*)(p + 4) = v1; *(float4*)(p + 8) = v2; *(float4*)(p + 12) = v3;
}

// ---------------- pass B: logits + softmax + weighted sum, fused ----------------
__global__ __launch_bounds__(320) void caps_pass_b(
    const float* __restrict__ x, const float* __restrict__ w,
    const float* __restrict__ o0, float* __restrict__ s1out)
{
    __shared__ float sw[NSTG * SWN];
    __shared__ float sx[NSTG * BT * DD1];
    __shared__ float sb[NSTG * BT * CC2];   // b1 exchange: [n_loc][b_loc][c]

    const int bc = blockIdx.x >> 5, nc = blockIdx.x & 31;
    const int b0 = bc * BT, n0 = nc * NT;
    const int tid = threadIdx.x;            // 320 = 32 b * 10 c
    const int bl = tid / 10;
    const int c  = tid - bl * 10;

    float o0r[16];
    {
        const float* p = o0 + (b0 + bl) * CD + c * DD2;
        float4 a = *(const float4*)p, b = *(const float4*)(p + 4),
               e = *(const float4*)(p + 8), d = *(const float4*)(p + 12);
        o0r[0]=a.x; o0r[1]=a.y; o0r[2]=a.z; o0r[3]=a.w; o0r[4]=b.x; o0r[5]=b.y; o0r[6]=b.z; o0r[7]=b.w;
        o0r[8]=e.x; o0r[9]=e.y; o0r[10]=e.z; o0r[11]=e.w; o0r[12]=d.x; o0r[13]=d.y; o0r[14]=d.z; o0r[15]=d.w;
    }
    float s1a[16];
#pragma unroll
    for (int d = 0; d < 16; ++d) s1a[d] = 0.f;

    for (int st = 0; st < NT / NSTG; ++st) {
        const int nb = n0 + st * NSTG;
#pragma unroll
        for (int it = 0; it < 4; ++it) {    // 1280 float4 / 320 threads
            int f = tid + it * 320;
            int cw = f >> 7;
            int j = (f & 127) << 2;
            float4 v = *(const float4*)(w + cw * WCN + nb * 128 + j);
            *(float4*)(sw + (j >> 7) * SWN + cw * CSTR + (j & 127)) = v;
        }
        if (tid < 256) {
            int b_l = tid >> 3;
            int j = (tid & 7) << 2;
            float4 v = *(const float4*)(x + (b0 + b_l) * XB + nb * DD1 + j);
            *(float4*)(sx + (j >> 3) * (BT * DD1) + b_l * DD1 + (j & 7)) = v;
        }
        __syncthreads();

        for (int nl = 0; nl < NSTG; ++nl) {
            float xr[8];
            {
                const float* p = sx + nl * (BT * DD1) + bl * DD1;
                float4 a = *(const float4*)p, b = *(const float4*)(p + 4);
                xr[0]=a.x; xr[1]=a.y; xr[2]=a.z; xr[3]=a.w; xr[4]=b.x; xr[5]=b.y; xr[6]=b.z; xr[7]=b.w;
            }
            float xh[16];
#pragma unroll
            for (int d = 0; d < 16; ++d) {
                const float* p = sw + nl * SWN + c * CSTR + d * DD1;
                float4 a = *(const float4*)p, b = *(const float4*)(p + 4);
                xh[d] = a.x*xr[0] + a.y*xr[1] + a.z*xr[2] + a.w*xr[3]
                      + b.x*xr[4] + b.y*xr[5] + b.z*xr[6] + b.w*xr[7];
            }
            float b1 = 0.f;
#pragma unroll
            for (int d = 0; d < 16; ++d) b1 += o0r[d] * xh[d];
            sb[nl * (BT * CC2) + tid] = b1;   // b_loc*10+c == tid
            __syncthreads();
            const float* rb = sb + nl * (BT * CC2) + bl * CC2;
            float m = rb[0];
#pragma unroll
            for (int jc = 1; jc < 10; ++jc) m = fmaxf(m, rb[jc]);
            float esum = 0.f;
#pragma unroll
            for (int jc = 0; jc < 10; ++jc) esum += __expf(rb[jc] - m);
            float c1 = __expf(rb[c] - m) / esum;
#pragma unroll
            for (int d = 0; d < 16; ++d) s1a[d] += c1 * xh[d];
        }
        // last per-n barrier already ordered all sw/sx reads before next stage's stores
    }

#pragma unroll
    for (int d = 0; d < 16; ++d)
        atomicAdd(&s1out[(b0 + bl) * CD + c * DD2 + d], s1a[d]);
}

// ---------------- final squash(s1) in place on d_out ----------------
__global__ void caps_squash_b(float* __restrict__ s)
{
    int t = blockIdx.x * blockDim.x + threadIdx.x;
    if (t >= BB * CC2) return;
    float* p = s + t * DD2;
    float4 v0 = *(float4*)(p), v1 = *(float4*)(p + 4), v2 = *(float4*)(p + 8), v3 = *(float4*)(p + 12);
    float ss = v0.x*v0.x + v0.y*v0.y + v0.z*v0.z + v0.w*v0.w
             + v1.x*v1.x + v1.y*v1.y + v1.z*v1.z + v1.w*v1.w
             + v2.x*v2.x + v2.y*v2.y + v2.z*v2.z + v2.w*v2.w
             + v3.x*v3.x + v3.y*v3.y + v3.z*v3.z + v3.w*v3.w;
    float sc = ss / (1.f + ss) / sqrtf(ss);
    v0.x*=sc; v0.y*=sc; v0.z*=sc; v0.w*=sc; v1.x*=sc; v1.y*=sc; v1.z*=sc; v1.w*=sc;
    v2.x*=sc; v2.y*=sc; v2.z*=sc; v2.w*=sc; v3.x*=sc; v3.y*=sc; v3.z*=sc; v3.w*=sc;
    *(float4*)(p) = v0; *(float4*)(p + 4) = v1; *(float4*)(p + 8) = v2; *(float4*)(p + 12) = v3;
}

extern "C" void kernel_launch(void* const* d_in, const int* in_sizes, int n_in,
                              void* d_out, int out_size, void* d_ws, size_t ws_size,
                              hipStream_t stream)
{
    (void)in_sizes; (void)n_in; (void)out_size; (void)ws_size;
    const float* x = (const float*)d_in[0];
    const float* w = (const float*)d_in[1];
    float* out = (float*)d_out;
    float* s0  = (float*)d_ws;            // 81920 floats; squashed in place -> o0

    hipMemsetAsync(s0, 0, BB * CD * sizeof(float), stream);
    hipMemsetAsync(out, 0, BB * CD * sizeof(float), stream);

    caps_pass_a <<<NBC * NNC, 256, 0, stream>>>(x, w, s0);
    caps_squash_a<<<(BB * CC2 + 255) / 256, 256, 0, stream>>>(s0);
    caps_pass_b <<<NBC * NNC, 320, 0, stream>>>(x, w, s0, out);
    caps_squash_b<<<(BB * CC2 + 255) / 256, 256, 0, stream>>>(out);
}